// Round 1
// baseline (4781.307 us; speedup 1.0000x reference)
//
#include <hip/hip_runtime.h>
#include <math.h>

// CrystalGNN edge-message layer, fp32 register-tiled baseline.
// Per block: 64 edges. H^T staged in LDS in 3 K-chunks of 64 (src/dst/E).
// Thread microtiles: m1 4e x 8j (K=192), a1 4e x 4j, a2 4e x 4j (K=48),
// m2 4e x 4j (K=128). Gated atomicAdd scatter into X_out (pre-copied from X).
// LDS row stride 66 floats -> 2-way max bank aliasing (free on gfx950).

#define NT 256
#define S 66            // LDS row stride in floats (even -> float2 aligned)

__global__ __launch_bounds__(256) void copy_kernel(const float4* __restrict__ src,
                                                   float4* __restrict__ dst, int n4) {
    int i = blockIdx.x * 256 + threadIdx.x;
    if (i < n4) dst[i] = src[i];
}

__global__ __launch_bounds__(256) void edge_kernel(
    const float* __restrict__ X, const float* __restrict__ E,
    const int* __restrict__ eidx,
    const float* __restrict__ aw1, const float* __restrict__ ab1,
    const float* __restrict__ aw2, const float* __restrict__ ab2,
    const float* __restrict__ aw3, const float* __restrict__ ab3,
    const float* __restrict__ mw1, const float* __restrict__ mb1,
    const float* __restrict__ mw2, const float* __restrict__ mb2,
    float* __restrict__ Xout, int n_edges)
{
    extern __shared__ char smem[];
    int*   si   = (int*)smem;                                   // 64 ints
    int*   di   = (int*)(smem + 256);                           // 64 ints
    float* gate = (float*)(smem + 512);                         // 64 f
    float* Hc   = (float*)(smem + 768);                         // 64 x S
    float* a2s  = Hc;                                           // alias (24 x S), Hc dead by then
    float* m1s  = (float*)(smem + 768 + 64 * S * 4);            // 128 x S
    float* a1s  = (float*)(smem + 768 + (64 + 128) * S * 4);    // 48 x S

    const int t  = threadIdx.x;
    const int e0 = blockIdx.x * 64;

    if (t < 64) {
        int eg = e0 + t;
        int v  = (eg < n_edges);
        si[t] = v ? eidx[eg] : 0;
        di[t] = v ? eidx[n_edges + eg] : 0;
    }

    const int eg4 = (t & 15) * 4;   // edge base of microtile (0..60)
    const int jg  = t >> 4;         // 0..15 (wave-uniform in groups of 4)

    float accM[4][8];
    float accA[4][4];
    #pragma unroll
    for (int a = 0; a < 4; a++) {
        #pragma unroll
        for (int b = 0; b < 8; b++) accM[a][b] = 0.f;
        #pragma unroll
        for (int b = 0; b < 4; b++) accA[a][b] = 0.f;
    }

    // ---- K-chunked staging + fused m1/a1 accumulation (K = 192 = 3 x 64) ----
    for (int kc = 0; kc < 3; kc++) {
        __syncthreads();
        #pragma unroll
        for (int i = 0; i < 16; i++) {
            int idx = i * NT + t;        // 0..4095
            int e   = idx >> 6;
            int k   = idx & 63;
            float v;
            if (kc == 0)      v = X[(size_t)si[e] * 64 + k];
            else if (kc == 1) v = X[(size_t)di[e] * 64 + k];
            else { int ee = e0 + e; v = (ee < n_edges) ? E[(size_t)ee * 64 + k] : 0.f; }
            Hc[k * S + e] = v;
        }
        __syncthreads();

        const float* wm = mw1 + (size_t)(kc * 64) * 128 + jg * 8;
        const float* wa = aw1 + (size_t)(kc * 64) * 48 + jg * 4;
        #pragma unroll 4
        for (int k = 0; k < 64; k++) {
            float2 h01 = *(const float2*)&Hc[k * S + eg4];
            float2 h23 = *(const float2*)&Hc[k * S + eg4 + 2];
            float h[4] = {h01.x, h01.y, h23.x, h23.y};
            float4 w0 = *(const float4*)(wm);
            float4 w1 = *(const float4*)(wm + 4);
            wm += 128;
            float wv[8] = {w0.x, w0.y, w0.z, w0.w, w1.x, w1.y, w1.z, w1.w};
            #pragma unroll
            for (int a = 0; a < 4; a++)
                #pragma unroll
                for (int b = 0; b < 8; b++)
                    accM[a][b] = fmaf(h[a], wv[b], accM[a][b]);
            if (jg < 12) {                     // waves 0..2 only (wave-uniform)
                float4 w2 = *(const float4*)(wa);
                float wv2[4] = {w2.x, w2.y, w2.z, w2.w};
                #pragma unroll
                for (int a = 0; a < 4; a++)
                    #pragma unroll
                    for (int b = 0; b < 4; b++)
                        accA[a][b] = fmaf(h[a], wv2[b], accA[a][b]);
            }
            wa += 48;
        }
    }

    // ---- store m1 = relu(H@mw1 + mb1), a1 = relu(H@aw1 + ab1), transposed ----
    #pragma unroll
    for (int b = 0; b < 8; b++) {
        int j = jg * 8 + b;
        float bias = mb1[j];
        #pragma unroll
        for (int a = 0; a < 4; a++)
            m1s[j * S + eg4 + a] = fmaxf(accM[a][b] + bias, 0.f);
    }
    if (jg < 12) {
        #pragma unroll
        for (int b = 0; b < 4; b++) {
            int j = jg * 4 + b;
            float bias = ab1[j];
            #pragma unroll
            for (int a = 0; a < 4; a++)
                a1s[j * S + eg4 + a] = fmaxf(accA[a][b] + bias, 0.f);
        }
    }
    __syncthreads();

    // ---- a2 = relu(a1 @ aw2 + ab2): [64 x 24], K=48 ----
    if (jg < 6) {
        float acc2[4][4] = {};
        const float* wp = aw2 + jg * 4;
        #pragma unroll 4
        for (int k = 0; k < 48; k++) {
            float2 h01 = *(const float2*)&a1s[k * S + eg4];
            float2 h23 = *(const float2*)&a1s[k * S + eg4 + 2];
            float4 w = *(const float4*)(wp); wp += 24;
            float h[4]  = {h01.x, h01.y, h23.x, h23.y};
            float wv[4] = {w.x, w.y, w.z, w.w};
            #pragma unroll
            for (int a = 0; a < 4; a++)
                #pragma unroll
                for (int b = 0; b < 4; b++)
                    acc2[a][b] = fmaf(h[a], wv[b], acc2[a][b]);
        }
        #pragma unroll
        for (int b = 0; b < 4; b++) {
            int j = jg * 4 + b;
            float bias = ab2[j];
            #pragma unroll
            for (int a = 0; a < 4; a++)
                a2s[j * S + eg4 + a] = fmaxf(acc2[a][b] + bias, 0.f);
        }
    }
    __syncthreads();

    // ---- a3 + sigmoid gate: [64], K=24 ----
    if (t < 64) {
        float s = ab3[0];
        #pragma unroll
        for (int k = 0; k < 24; k++)
            s = fmaf(a2s[k * S + t], aw3[k], s);
        gate[t] = 1.f / (1.f + expf(-s));
    }
    __syncthreads();

    // ---- m2 = m1 @ mw2 + mb2: [64 x 64], K=128; gate + atomic scatter ----
    {
        float acc2[4][4] = {};
        const float* wp = mw2 + jg * 4;
        #pragma unroll 4
        for (int k = 0; k < 128; k++) {
            float2 h01 = *(const float2*)&m1s[k * S + eg4];
            float2 h23 = *(const float2*)&m1s[k * S + eg4 + 2];
            float4 w = *(const float4*)(wp); wp += 64;
            float h[4]  = {h01.x, h01.y, h23.x, h23.y};
            float wv[4] = {w.x, w.y, w.z, w.w};
            #pragma unroll
            for (int a = 0; a < 4; a++)
                #pragma unroll
                for (int b = 0; b < 4; b++)
                    acc2[a][b] = fmaf(h[a], wv[b], acc2[a][b]);
        }
        float bias[4];
        #pragma unroll
        for (int b = 0; b < 4; b++) bias[b] = mb2[jg * 4 + b];
        #pragma unroll
        for (int a = 0; a < 4; a++) {
            int ee = eg4 + a;
            if (e0 + ee < n_edges) {
                float g = gate[ee];
                float* outp = Xout + (size_t)di[ee] * 64 + jg * 4;
                #pragma unroll
                for (int b = 0; b < 4; b++)
                    atomicAdd(outp + b, (acc2[a][b] + bias[b]) * g);
            }
        }
    }
}

extern "C" void kernel_launch(void* const* d_in, const int* in_sizes, int n_in,
                              void* d_out, int out_size, void* d_ws, size_t ws_size,
                              hipStream_t stream) {
    const float* X   = (const float*)d_in[0];
    const float* E   = (const float*)d_in[1];
    const int*   eidx= (const int*)d_in[4];
    const float* aw1 = (const float*)d_in[5];
    const float* ab1 = (const float*)d_in[6];
    const float* aw2 = (const float*)d_in[7];
    const float* ab2 = (const float*)d_in[8];
    const float* aw3 = (const float*)d_in[9];
    const float* ab3 = (const float*)d_in[10];
    const float* mw1 = (const float*)d_in[11];
    const float* mb1 = (const float*)d_in[12];
    const float* mw2 = (const float*)d_in[13];
    const float* mb2 = (const float*)d_in[14];
    float* Xout = (float*)d_out;

    int n_node_elems = in_sizes[0];          // n_nodes * 64
    int n_edges      = in_sizes[1] / 64;

    int n4 = n_node_elems / 4;
    copy_kernel<<<(n4 + 255) / 256, 256, 0, stream>>>((const float4*)X, (float4*)Xout, n4);

    int ntiles = (n_edges + 63) / 64;
    size_t shmem = 768 + (size_t)(64 + 128 + 48) * S * 4;   // 64128 B
    edge_kernel<<<ntiles, 256, shmem, stream>>>(X, E, eidx, aw1, ab1, aw2, ab2,
                                                aw3, ab3, mw1, mb1, mw2, mb2,
                                                Xout, n_edges);
}

// Round 2
// 1270.707 us; speedup vs baseline: 3.7627x; 3.7627x over previous
//
#include <hip/hip_runtime.h>
#include <math.h>

// CrystalGNN edge-message layer, bf16 MFMA version.
// Per block: 64 edges. H (64x192) staged bf16 in LDS; GEMM1 computes
// [m1|a1] = relu(H @ [mw1|aw1|0] + b) via 16x16x32 bf16 MFMA (j padded to 192).
// res1 overwrites H in LDS. GEMM2: m2 = res1[:, :128]@mw2 (K=128) and
// a2 = res1[:,128:192]@aw2pad (K=64, zero-padded) on MFMA. a3+sigmoid on one
// wave (VALU). Gated atomicAdd scatter into X_out (pre-copied from X).
// Weights pre-transposed/converted to bf16 in d_ws by prep_kernel.

typedef __attribute__((ext_vector_type(4))) short short4v;
typedef __attribute__((ext_vector_type(8))) short short8v;
typedef __attribute__((ext_vector_type(4))) float float4v;

#define RS 400          // Hs/res1s row stride in BYTES (200 bf16; mult of 16; bank-offset 4 dwords)
#define RA 80           // a2s row stride in bytes

// ws byte offsets
#define OFF_W1T 0                      // 192 x 192 bf16 = 73728
#define OFF_W2T 73728                  // 64 x 128 bf16  = 16384
#define OFF_W3T 90112                  // 32 x 64 bf16   = 4096
#define OFF_B1  94208                  // 208 f32        = 832
#define OFF_AB2 95040                  // 32 f32         = 128
#define OFF_AW3 95168                  // 32 f32         = 128

static __device__ __forceinline__ short f2bf(float f) {
    union { float f; unsigned u; } v; v.f = f;
    unsigned r = (v.u + 0x7fffu + ((v.u >> 16) & 1u)) >> 16;
    return (short)r;
}
static __device__ __forceinline__ float bf2f(short s) {
    union { unsigned u; float f; } v; v.u = ((unsigned)(unsigned short)s) << 16;
    return v.f;
}

__global__ __launch_bounds__(256) void copy_kernel(const float4* __restrict__ src,
                                                   float4* __restrict__ dst, int n4) {
    int i = blockIdx.x * 256 + threadIdx.x;
    if (i < n4) dst[i] = src[i];
}

__global__ __launch_bounds__(256) void prep_kernel(
    const float* __restrict__ mw1, const float* __restrict__ aw1,
    const float* __restrict__ mw2, const float* __restrict__ aw2,
    const float* __restrict__ mb1, const float* __restrict__ ab1,
    const float* __restrict__ ab2, const float* __restrict__ aw3,
    char* __restrict__ ws)
{
    unsigned short* W1T = (unsigned short*)(ws + OFF_W1T);
    unsigned short* W2T = (unsigned short*)(ws + OFF_W2T);
    unsigned short* W3T = (unsigned short*)(ws + OFF_W3T);
    float* B1  = (float*)(ws + OFF_B1);
    float* AB2 = (float*)(ws + OFF_AB2);
    float* AW3 = (float*)(ws + OFF_AW3);

    int i = blockIdx.x * 256 + threadIdx.x;
    const int n1 = 192 * 192;           // W1T
    const int n2 = 64 * 128;            // W2T
    const int n3 = 32 * 64;             // W3T
    if (i < n1) {
        int j = i / 192, k = i % 192;
        float v = 0.f;
        if (j < 128)      v = mw1[(size_t)k * 128 + j];
        else if (j < 176) v = aw1[(size_t)k * 48 + (j - 128)];
        W1T[i] = (unsigned short)f2bf(v);
    } else if (i < n1 + n2) {
        int r = i - n1; int j = r >> 7, k = r & 127;
        W2T[r] = (unsigned short)f2bf(mw2[(size_t)k * 64 + j]);
    } else if (i < n1 + n2 + n3) {
        int r = i - n1 - n2; int j = r >> 6, k = r & 63;
        float v = (j < 24 && k < 48) ? aw2[(size_t)k * 24 + j] : 0.f;
        W3T[r] = (unsigned short)f2bf(v);
    } else if (i < n1 + n2 + n3 + 208) {
        int j = i - n1 - n2 - n3;
        float v = 0.f;
        if (j < 128)      v = mb1[j];
        else if (j < 176) v = ab1[j - 128];
        B1[j] = v;
    } else if (i < n1 + n2 + n3 + 208 + 32) {
        int j = i - n1 - n2 - n3 - 208;
        AB2[j] = (j < 24) ? ab2[j] : 0.f;
    } else if (i < n1 + n2 + n3 + 208 + 64) {
        int k = i - n1 - n2 - n3 - 208 - 32;
        AW3[k] = (k < 24) ? aw3[k] : 0.f;
    }
}

__global__ __launch_bounds__(256) void edge_kernel(
    const float* __restrict__ X, const float* __restrict__ E,
    const int* __restrict__ eidx, const char* __restrict__ ws,
    const float* __restrict__ ab3, const float* __restrict__ mb2,
    float* __restrict__ Xout, int n_edges)
{
    const unsigned short* W1T = (const unsigned short*)(ws + OFF_W1T);
    const unsigned short* W2T = (const unsigned short*)(ws + OFF_W2T);
    const unsigned short* W3T = (const unsigned short*)(ws + OFF_W3T);
    const float* B1  = (const float*)(ws + OFF_B1);
    const float* AB2 = (const float*)(ws + OFF_AB2);
    const float* AW3 = (const float*)(ws + OFF_AW3);

    extern __shared__ char smem[];
    int*   si   = (int*)smem;            // 64 ints
    int*   di   = (int*)(smem + 256);    // 64 ints
    float* gate = (float*)(smem + 512);  // 64 f32
    char*  a2s  = smem + 768;            // 64 x RA = 5120 B
    char*  Hs   = smem + 768 + 5120;     // 64 x RS = 25600 B (res1s aliases)

    const int t    = threadIdx.x;
    const int w    = t >> 6;
    const int lane = t & 63;
    const int n16  = lane & 15;
    const int q    = lane >> 4;
    const int e0   = blockIdx.x * 64;

    if (t < 64) {
        int eg = e0 + t; if (eg >= n_edges) eg = n_edges - 1;
        si[t] = eidx[eg];
        di[t] = eidx[n_edges + eg];
    }
    __syncthreads();

    // ---- stage H = [Xsrc | Xdst | E] as bf16, row-major [64][200*2B] ----
    #pragma unroll
    for (int s = 0; s < 3; s++) {
        #pragma unroll
        for (int i = 0; i < 4; i++) {
            int idx = i * 256 + t;           // 0..1023
            int e = idx >> 4, k = (idx & 15) * 4;
            const float* p;
            if (s == 0)      p = X + (size_t)si[e] * 64 + k;
            else if (s == 1) p = X + (size_t)di[e] * 64 + k;
            else { int ee = e0 + e; if (ee >= n_edges) ee = n_edges - 1;
                   p = E + (size_t)ee * 64 + k; }
            float4 v = *(const float4*)p;
            short4v b; b[0] = f2bf(v.x); b[1] = f2bf(v.y); b[2] = f2bf(v.z); b[3] = f2bf(v.w);
            *(short4v*)(Hs + e * RS + (s * 64 + k) * 2) = b;
        }
    }
    __syncthreads();

    // ---- GEMM1: res1[64 x 192] = relu(H @ W1cat + b1), K = 192 ----
    // j-tiles 0..11 (192 cols: 0..127 m1, 128..175 a1, 176..191 zero-pad).
    // wave w owns jt = w, w+4, w+8. 4 e-tiles each.
    float4v acc1[3][4];
    #pragma unroll
    for (int a = 0; a < 3; a++)
        #pragma unroll
        for (int b = 0; b < 4; b++)
            acc1[a][b] = (float4v){0.f, 0.f, 0.f, 0.f};

    #pragma unroll
    for (int ks = 0; ks < 6; ks++) {
        short8v af[4];
        #pragma unroll
        for (int et = 0; et < 4; et++)
            af[et] = *(const short8v*)(Hs + (et * 16 + n16) * RS + (ks * 32 + q * 8) * 2);
        #pragma unroll
        for (int ji = 0; ji < 3; ji++) {
            int jt = w + ji * 4;
            short8v bf = *(const short8v*)(W1T + (size_t)(jt * 16 + n16) * 192 + ks * 32 + q * 8);
            #pragma unroll
            for (int et = 0; et < 4; et++)
                acc1[ji][et] = __builtin_amdgcn_mfma_f32_16x16x32_bf16(af[et], bf, acc1[ji][et], 0, 0, 0);
        }
    }
    __syncthreads();   // all Hs reads complete before overwrite

    // ---- epilogue GEMM1: relu+bias, store bf16 over Hs (res1s) ----
    #pragma unroll
    for (int ji = 0; ji < 3; ji++) {
        int jt = w + ji * 4;
        int j  = jt * 16 + n16;
        float bias = B1[j];
        #pragma unroll
        for (int et = 0; et < 4; et++) {
            #pragma unroll
            for (int r = 0; r < 4; r++) {
                int e = et * 16 + q * 4 + r;
                float v = fmaxf(acc1[ji][et][r] + bias, 0.f);
                *(short*)(Hs + e * RS + j * 2) = f2bf(v);
            }
        }
    }
    __syncthreads();

    // ---- GEMM2: m2 = res1[:, :128] @ W2 (K=128), a2 = res1[:,128:192] @ W3 (K=64) ----
    float4v acc2[4];
    float4v acc3[2];
    #pragma unroll
    for (int a = 0; a < 4; a++) acc2[a] = (float4v){0.f, 0.f, 0.f, 0.f};
    #pragma unroll
    for (int a = 0; a < 2; a++) acc3[a] = (float4v){0.f, 0.f, 0.f, 0.f};

    #pragma unroll
    for (int ks = 0; ks < 4; ks++) {
        short8v bf = *(const short8v*)(W2T + (size_t)(w * 16 + n16) * 128 + ks * 32 + q * 8);
        #pragma unroll
        for (int et = 0; et < 4; et++) {
            short8v af = *(const short8v*)(Hs + (et * 16 + n16) * RS + (ks * 32 + q * 8) * 2);
            acc2[et] = __builtin_amdgcn_mfma_f32_16x16x32_bf16(af, bf, acc2[et], 0, 0, 0);
        }
    }
    #pragma unroll
    for (int ks = 0; ks < 2; ks++) {
        short8v af = *(const short8v*)(Hs + (w * 16 + n16) * RS + 256 + ks * 64 + q * 16);
        #pragma unroll
        for (int jt2 = 0; jt2 < 2; jt2++) {
            short8v bf = *(const short8v*)(W3T + (size_t)(jt2 * 16 + n16) * 64 + ks * 32 + q * 8);
            acc3[jt2] = __builtin_amdgcn_mfma_f32_16x16x32_bf16(af, bf, acc3[jt2], 0, 0, 0);
        }
    }

    // ---- a2 epilogue: relu+bias, store bf16 to a2s (separate region) ----
    #pragma unroll
    for (int jt2 = 0; jt2 < 2; jt2++) {
        int j = jt2 * 16 + n16;
        float bias = AB2[j];
        #pragma unroll
        for (int r = 0; r < 4; r++) {
            int e = w * 16 + q * 4 + r;
            float v = fmaxf(acc3[jt2][r] + bias, 0.f);
            *(short*)(a2s + e * RA + j * 2) = f2bf(v);
        }
    }
    __syncthreads();

    // ---- a3 + sigmoid gate (one wave) ----
    if (t < 64) {
        short8v r0 = *(const short8v*)(a2s + t * RA);
        short8v r1 = *(const short8v*)(a2s + t * RA + 16);
        short8v r2 = *(const short8v*)(a2s + t * RA + 32);
        float s = ab3[0];
        #pragma unroll
        for (int k = 0; k < 8; k++) s = fmaf(bf2f(r0[k]), AW3[k], s);
        #pragma unroll
        for (int k = 0; k < 8; k++) s = fmaf(bf2f(r1[k]), AW3[8 + k], s);
        #pragma unroll
        for (int k = 0; k < 8; k++) s = fmaf(bf2f(r2[k]), AW3[16 + k], s);
        gate[t] = 1.f / (1.f + expf(-s));
    }
    __syncthreads();

    // ---- m2 epilogue: gate * (m2 + bias), atomic scatter ----
    {
        int j = w * 16 + n16;
        float bias = mb2[j];
        #pragma unroll
        for (int et = 0; et < 4; et++) {
            #pragma unroll
            for (int r = 0; r < 4; r++) {
                int e = et * 16 + q * 4 + r;
                if (e0 + e < n_edges) {
                    float g = gate[e];
                    atomicAdd(Xout + (size_t)di[e] * 64 + j, (acc2[et][r] + bias) * g);
                }
            }
        }
    }
}

extern "C" void kernel_launch(void* const* d_in, const int* in_sizes, int n_in,
                              void* d_out, int out_size, void* d_ws, size_t ws_size,
                              hipStream_t stream) {
    const float* X   = (const float*)d_in[0];
    const float* E   = (const float*)d_in[1];
    const int*   eidx= (const int*)d_in[4];
    const float* aw1 = (const float*)d_in[5];
    const float* ab1 = (const float*)d_in[6];
    const float* aw2 = (const float*)d_in[7];
    const float* ab2 = (const float*)d_in[8];
    const float* aw3 = (const float*)d_in[9];
    const float* ab3 = (const float*)d_in[10];
    const float* mw1 = (const float*)d_in[11];
    const float* mb1 = (const float*)d_in[12];
    const float* mw2 = (const float*)d_in[13];
    const float* mb2 = (const float*)d_in[14];
    float* Xout = (float*)d_out;

    int n_node_elems = in_sizes[0];
    int n_edges      = in_sizes[1] / 64;

    int n4 = n_node_elems / 4;
    copy_kernel<<<(n4 + 255) / 256, 256, 0, stream>>>((const float4*)X, (float4*)Xout, n4);

    prep_kernel<<<(192 * 192 + 64 * 128 + 32 * 64 + 208 + 64 + 255) / 256, 256, 0, stream>>>(
        mw1, aw1, mw2, aw2, mb1, ab1, ab2, aw3, (char*)d_ws);

    int ntiles = (n_edges + 63) / 64;
    size_t shmem = 768 + 5120 + 64 * RS;   // 31488 B
    edge_kernel<<<ntiles, 256, shmem, stream>>>(X, E, eidx, (const char*)d_ws,
                                                ab3, mb2, Xout, n_edges);
}

// Round 3
// 1073.574 us; speedup vs baseline: 4.4536x; 1.1836x over previous
//
#include <hip/hip_runtime.h>
#include <math.h>

// CrystalGNN edge-message layer — persistent, software-pipelined bf16 MFMA.
// 512 blocks (2/CU), each grid-strides over 64-edge tiles. Weight fragments
// live in VGPRs for the whole kernel. Per iteration: issue global loads for
// tile k+1 (H rows) + eidx for tile k+2, then GEMM1 on tile k (pure
// ds_read_b128 + MFMA), epilogue, GEMM2/a2, gate, gated atomic scatter.
// LDS: double-buffered H (2 x 25600 B, stride 400 B = conflict-free b128),
// triple-buffered index slots, a2 scratch. Total 58112 B -> 2 blocks/CU.

typedef __attribute__((ext_vector_type(4))) short short4v;
typedef __attribute__((ext_vector_type(8))) short short8v;
typedef __attribute__((ext_vector_type(4))) float float4v;

#define RS 400          // H/res1 row stride in bytes
#define RA 80           // a2s row stride in bytes
#define NBLK 512

#define OFF_W1T 0                      // 192x192 bf16
#define OFF_W2T 73728                  // 64x128 bf16
#define OFF_W3T 90112                  // 32x64 bf16
#define OFF_B1  94208                  // 208 f32
#define OFF_AB2 95040                  // 32 f32
#define OFF_AW3 95168                  // 32 f32

static __device__ __forceinline__ short f2bf(float f) {
    union { float f; unsigned u; } v; v.f = f;
    unsigned r = (v.u + 0x7fffu + ((v.u >> 16) & 1u)) >> 16;
    return (short)r;
}
static __device__ __forceinline__ float bf2f(short s) {
    union { unsigned u; float f; } v; v.u = ((unsigned)(unsigned short)s) << 16;
    return v.f;
}
static __device__ __forceinline__ int imin(int a, int b) { return a < b ? a : b; }

__global__ __launch_bounds__(256) void copy_kernel(const float4* __restrict__ src,
                                                   float4* __restrict__ dst, int n4) {
    int i = blockIdx.x * 256 + threadIdx.x;
    if (i < n4) dst[i] = src[i];
}

__global__ __launch_bounds__(256) void prep_kernel(
    const float* __restrict__ mw1, const float* __restrict__ aw1,
    const float* __restrict__ mw2, const float* __restrict__ aw2,
    const float* __restrict__ mb1, const float* __restrict__ ab1,
    const float* __restrict__ ab2, const float* __restrict__ aw3,
    char* __restrict__ ws)
{
    unsigned short* W1T = (unsigned short*)(ws + OFF_W1T);
    unsigned short* W2T = (unsigned short*)(ws + OFF_W2T);
    unsigned short* W3T = (unsigned short*)(ws + OFF_W3T);
    float* B1  = (float*)(ws + OFF_B1);
    float* AB2 = (float*)(ws + OFF_AB2);
    float* AW3 = (float*)(ws + OFF_AW3);

    int i = blockIdx.x * 256 + threadIdx.x;
    const int n1 = 192 * 192, n2 = 64 * 128, n3 = 32 * 64;
    if (i < n1) {
        int j = i / 192, k = i % 192;
        float v = 0.f;
        if (j < 128)      v = mw1[(size_t)k * 128 + j];
        else if (j < 176) v = aw1[(size_t)k * 48 + (j - 128)];
        W1T[i] = (unsigned short)f2bf(v);
    } else if (i < n1 + n2) {
        int r = i - n1; int j = r >> 7, k = r & 127;
        W2T[r] = (unsigned short)f2bf(mw2[(size_t)k * 64 + j]);
    } else if (i < n1 + n2 + n3) {
        int r = i - n1 - n2; int j = r >> 6, k = r & 63;
        float v = (j < 24 && k < 48) ? aw2[(size_t)k * 24 + j] : 0.f;
        W3T[r] = (unsigned short)f2bf(v);
    } else if (i < n1 + n2 + n3 + 208) {
        int j = i - n1 - n2 - n3;
        float v = 0.f;
        if (j < 128)      v = mb1[j];
        else if (j < 176) v = ab1[j - 128];
        B1[j] = v;
    } else if (i < n1 + n2 + n3 + 208 + 32) {
        int j = i - n1 - n2 - n3 - 208;
        AB2[j] = (j < 24) ? ab2[j] : 0.f;
    } else if (i < n1 + n2 + n3 + 208 + 64) {
        int k = i - n1 - n2 - n3 - 208 - 32;
        AW3[k] = (k < 24) ? aw3[k] : 0.f;
    }
}

__global__ __launch_bounds__(256, 2) void edge_kernel(
    const float* __restrict__ X, const float* __restrict__ E,
    const int* __restrict__ eidx, const char* __restrict__ ws,
    const float* __restrict__ ab3, const float* __restrict__ mb2,
    float* __restrict__ Xout, int n_edges)
{
    const unsigned short* W1T = (const unsigned short*)(ws + OFF_W1T);
    const unsigned short* W2T = (const unsigned short*)(ws + OFF_W2T);
    const unsigned short* W3T = (const unsigned short*)(ws + OFF_W3T);
    const float* B1  = (const float*)(ws + OFF_B1);
    const float* AB2 = (const float*)(ws + OFF_AB2);
    const float* AW3 = (const float*)(ws + OFF_AW3);

    extern __shared__ char smem[];
    int*   si   = (int*)smem;              // 3 x 64
    int*   di   = (int*)(smem + 768);      // 3 x 64
    float* gate = (float*)(smem + 1536);   // 64
    char*  a2s  = smem + 1792;             // 64 x RA = 5120
    char*  Hs0  = smem + 6912;             // 64 x RS = 25600
    char*  Hs1  = smem + 32512;            // 64 x RS = 25600  (total 58112)

    const int t    = threadIdx.x;
    const int w    = t >> 6;
    const int lane = t & 63;
    const int n16  = lane & 15;
    const int q    = lane >> 4;
    const int ntiles = (n_edges + 63) >> 6;
    const int nb = gridDim.x;

    int tile = blockIdx.x;
    if (tile >= ntiles) return;

    // ---- preload weight fragments into VGPRs (kernel lifetime) ----
    short8v w1f[3][6];
    float   b1m[3];
    #pragma unroll
    for (int ji = 0; ji < 3; ji++) {
        int jt = w + ji * 4;
        #pragma unroll
        for (int ks = 0; ks < 6; ks++)
            w1f[ji][ks] = *(const short8v*)(W1T + (size_t)(jt * 16 + n16) * 192 + ks * 32 + q * 8);
        b1m[ji] = B1[jt * 16 + n16];
    }
    short8v w2f[4];
    #pragma unroll
    for (int ks = 0; ks < 4; ks++)
        w2f[ks] = *(const short8v*)(W2T + (size_t)(w * 16 + n16) * 128 + ks * 32 + q * 8);
    short8v w3f[2][2];
    float   ab2v[2];
    #pragma unroll
    for (int jt2 = 0; jt2 < 2; jt2++) {
        #pragma unroll
        for (int ks = 0; ks < 2; ks++)
            w3f[jt2][ks] = *(const short8v*)(W3T + (size_t)(jt2 * 16 + n16) * 64 + ks * 32 + q * 8);
        ab2v[jt2] = AB2[jt2 * 16 + n16];
    }
    const float mb2v = mb2[w * 16 + n16];
    const float ab3v = ab3[0];

    const int eb = t >> 4;          // 0..15 (row base for staging)
    const int k4 = (t & 15) * 4;    // float col base for staging

    // ---- prologue: indices for tile (slot 0) and tile+nb (slot 1) ----
    if (t < 64) {
        int a0 = imin(tile * 64 + t, n_edges - 1);
        int t1 = imin(tile + nb, ntiles - 1);
        int a1 = imin(t1 * 64 + t, n_edges - 1);
        si[t]      = eidx[a0];  di[t]      = eidx[n_edges + a0];
        si[64 + t] = eidx[a1];  di[64 + t] = eidx[n_edges + a1];
    }
    __syncthreads();
    // stage tile -> Hs0
    {
        int e0 = tile * 64;
        #pragma unroll
        for (int i = 0; i < 4; i++) {
            int e = i * 16 + eb;
            float4 vx = *(const float4*)(X + (size_t)si[e] * 64 + k4);
            float4 vy = *(const float4*)(X + (size_t)di[e] * 64 + k4);
            float4 vz = *(const float4*)(E + (size_t)imin(e0 + e, n_edges - 1) * 64 + k4);
            short4v b;
            b[0]=f2bf(vx.x); b[1]=f2bf(vx.y); b[2]=f2bf(vx.z); b[3]=f2bf(vx.w);
            *(short4v*)(Hs0 + e * RS + k4 * 2) = b;
            b[0]=f2bf(vy.x); b[1]=f2bf(vy.y); b[2]=f2bf(vy.z); b[3]=f2bf(vy.w);
            *(short4v*)(Hs0 + e * RS + 128 + k4 * 2) = b;
            b[0]=f2bf(vz.x); b[1]=f2bf(vz.y); b[2]=f2bf(vz.z); b[3]=f2bf(vz.w);
            *(short4v*)(Hs0 + e * RS + 256 + k4 * 2) = b;
        }
    }
    __syncthreads();

    char* cur = Hs0;
    char* nxt = Hs1;
    int scur = 0;

    for (; tile < ntiles; tile += nb) {
        int snxt = scur + 1; if (snxt == 3) snxt = 0;
        int spf  = snxt + 1; if (spf  == 3) spf  = 0;
        int tnext = imin(tile + nb, ntiles - 1);
        int tpf   = imin(tile + 2 * nb, ntiles - 1);

        // ---- A: prefetch eidx for tile+2*nb into registers ----
        int pfs = 0, pfd = 0;
        if (t < 64) {
            int a = imin(tpf * 64 + t, n_edges - 1);
            pfs = eidx[a];
            pfd = eidx[n_edges + a];
        }

        // ---- B: issue global loads for tile+nb H rows ----
        float4 vx[4], vy[4], vz[4];
        {
            int e0n = tnext * 64;
            #pragma unroll
            for (int i = 0; i < 4; i++) {
                int e = i * 16 + eb;
                int es = si[snxt * 64 + e];
                int ed = di[snxt * 64 + e];
                vz[i] = *(const float4*)(E + (size_t)imin(e0n + e, n_edges - 1) * 64 + k4);
                vx[i] = *(const float4*)(X + (size_t)es * 64 + k4);
                vy[i] = *(const float4*)(X + (size_t)ed * 64 + k4);
            }
        }

        // ---- C: GEMM1 on cur (weights in regs, A from LDS) ----
        float4v acc1[3][4];
        #pragma unroll
        for (int a = 0; a < 3; a++)
            #pragma unroll
            for (int b = 0; b < 4; b++)
                acc1[a][b] = (float4v){0.f, 0.f, 0.f, 0.f};
        #pragma unroll
        for (int ks = 0; ks < 6; ks++) {
            short8v af[4];
            #pragma unroll
            for (int et = 0; et < 4; et++)
                af[et] = *(const short8v*)(cur + (et * 16 + n16) * RS + (ks * 32 + q * 8) * 2);
            #pragma unroll
            for (int ji = 0; ji < 3; ji++)
                #pragma unroll
                for (int et = 0; et < 4; et++)
                    acc1[ji][et] = __builtin_amdgcn_mfma_f32_16x16x32_bf16(af[et], w1f[ji][ks], acc1[ji][et], 0, 0, 0);
        }
        __syncthreads();   // cur reads done; nxt free; slot spf free

        // ---- D: res1 epilogue -> cur ----
        #pragma unroll
        for (int ji = 0; ji < 3; ji++) {
            int j = (w + ji * 4) * 16 + n16;
            float bias = b1m[ji];
            #pragma unroll
            for (int et = 0; et < 4; et++)
                #pragma unroll
                for (int r = 0; r < 4; r++) {
                    int e = et * 16 + q * 4 + r;
                    *(short*)(cur + e * RS + j * 2) = f2bf(fmaxf(acc1[ji][et][r] + bias, 0.f));
                }
        }
        // ---- E: write staged tile+nb -> nxt ----
        #pragma unroll
        for (int i = 0; i < 4; i++) {
            int e = i * 16 + eb;
            short4v b;
            b[0]=f2bf(vx[i].x); b[1]=f2bf(vx[i].y); b[2]=f2bf(vx[i].z); b[3]=f2bf(vx[i].w);
            *(short4v*)(nxt + e * RS + k4 * 2) = b;
            b[0]=f2bf(vy[i].x); b[1]=f2bf(vy[i].y); b[2]=f2bf(vy[i].z); b[3]=f2bf(vy[i].w);
            *(short4v*)(nxt + e * RS + 128 + k4 * 2) = b;
            b[0]=f2bf(vz[i].x); b[1]=f2bf(vz[i].y); b[2]=f2bf(vz[i].z); b[3]=f2bf(vz[i].w);
            *(short4v*)(nxt + e * RS + 256 + k4 * 2) = b;
        }
        // ---- F: write prefetched indices -> slot spf ----
        if (t < 64) { si[spf * 64 + t] = pfs; di[spf * 64 + t] = pfd; }
        __syncthreads();

        // ---- G: GEMM2 (m2, K=128) + GEMM3 (a2, K=64) on cur res1 ----
        float4v acc2[4], acc3[2];
        #pragma unroll
        for (int a = 0; a < 4; a++) acc2[a] = (float4v){0.f, 0.f, 0.f, 0.f};
        #pragma unroll
        for (int a = 0; a < 2; a++) acc3[a] = (float4v){0.f, 0.f, 0.f, 0.f};
        #pragma unroll
        for (int ks = 0; ks < 4; ks++) {
            #pragma unroll
            for (int et = 0; et < 4; et++) {
                short8v af = *(const short8v*)(cur + (et * 16 + n16) * RS + (ks * 32 + q * 8) * 2);
                acc2[et] = __builtin_amdgcn_mfma_f32_16x16x32_bf16(af, w2f[ks], acc2[et], 0, 0, 0);
            }
        }
        #pragma unroll
        for (int ks = 0; ks < 2; ks++) {
            short8v af = *(const short8v*)(cur + (w * 16 + n16) * RS + 256 + ks * 64 + q * 16);
            #pragma unroll
            for (int jt2 = 0; jt2 < 2; jt2++)
                acc3[jt2] = __builtin_amdgcn_mfma_f32_16x16x32_bf16(af, w3f[jt2][ks], acc3[jt2], 0, 0, 0);
        }
        // ---- H: a2 epilogue -> a2s ----
        #pragma unroll
        for (int jt2 = 0; jt2 < 2; jt2++) {
            int j = jt2 * 16 + n16;
            float bias = ab2v[jt2];
            #pragma unroll
            for (int r = 0; r < 4; r++) {
                int e = w * 16 + q * 4 + r;
                *(short*)(a2s + e * RA + j * 2) = f2bf(fmaxf(acc3[jt2][r] + bias, 0.f));
            }
        }
        __syncthreads();

        // ---- I: a3 + sigmoid gate ----
        if (t < 64) {
            short8v r0 = *(const short8v*)(a2s + t * RA);
            short8v r1 = *(const short8v*)(a2s + t * RA + 16);
            short8v r2 = *(const short8v*)(a2s + t * RA + 32);
            float s = ab3v;
            #pragma unroll
            for (int k = 0; k < 8; k++) s = fmaf(bf2f(r0[k]), AW3[k], s);
            #pragma unroll
            for (int k = 0; k < 8; k++) s = fmaf(bf2f(r1[k]), AW3[8 + k], s);
            #pragma unroll
            for (int k = 0; k < 8; k++) s = fmaf(bf2f(r2[k]), AW3[16 + k], s);
            gate[t] = 1.f / (1.f + expf(-s));
        }
        __syncthreads();

        // ---- J: gated atomic scatter ----
        {
            int j = w * 16 + n16;
            int e0 = tile * 64;
            #pragma unroll
            for (int et = 0; et < 4; et++)
                #pragma unroll
                for (int r = 0; r < 4; r++) {
                    int e = et * 16 + q * 4 + r;
                    if (e0 + e < n_edges) {
                        float g = gate[e];
                        atomicAdd(Xout + (size_t)di[scur * 64 + e] * 64 + j,
                                  (acc2[et][r] + mb2v) * g);
                    }
                }
        }

        // rotate buffers/slots
        char* tmp = cur; cur = nxt; nxt = tmp;
        scur = snxt;
    }
}

extern "C" void kernel_launch(void* const* d_in, const int* in_sizes, int n_in,
                              void* d_out, int out_size, void* d_ws, size_t ws_size,
                              hipStream_t stream) {
    const float* X   = (const float*)d_in[0];
    const float* E   = (const float*)d_in[1];
    const int*   eidx= (const int*)d_in[4];
    const float* aw1 = (const float*)d_in[5];
    const float* ab1 = (const float*)d_in[6];
    const float* aw2 = (const float*)d_in[7];
    const float* ab2 = (const float*)d_in[8];
    const float* aw3 = (const float*)d_in[9];
    const float* ab3 = (const float*)d_in[10];
    const float* mw1 = (const float*)d_in[11];
    const float* mb1 = (const float*)d_in[12];
    const float* mw2 = (const float*)d_in[13];
    const float* mb2 = (const float*)d_in[14];
    float* Xout = (float*)d_out;

    int n_node_elems = in_sizes[0];
    int n_edges      = in_sizes[1] / 64;

    int n4 = n_node_elems / 4;
    copy_kernel<<<(n4 + 255) / 256, 256, 0, stream>>>((const float4*)X, (float4*)Xout, n4);

    prep_kernel<<<(192 * 192 + 64 * 128 + 32 * 64 + 208 + 64 + 255) / 256, 256, 0, stream>>>(
        mw1, aw1, mw2, aw2, mb1, ab1, ab2, aw3, (char*)d_ws);

    int ntiles = (n_edges + 63) / 64;
    int grid = NBLK < ntiles ? NBLK : ntiles;
    size_t shmem = 58112;
    edge_kernel<<<grid, 256, shmem, stream>>>(X, E, eidx, (const char*)d_ws,
                                              ab3, mb2, Xout, n_edges);
}